// Round 9
// baseline (409.840 us; speedup 1.0000x reference)
//
#include <hip/hip_runtime.h>
#include <hip/hip_bf16.h>

#define R_RES 384
#define S_SEQ 128
#define CM 256
#define CC 32
#define CZ 128

typedef __attribute__((ext_vector_type(8))) short bf16x8;
typedef __attribute__((ext_vector_type(4))) float f32x4;
typedef __attribute__((ext_vector_type(4))) int i32x4;

__device__ __forceinline__ short tobf16(float f) {
    union { __hip_bfloat16 h; short s; } u;
    u.h = __float2bfloat16(f);
    return u.s;
}

// lgkm-only barrier: LDS visibility without draining outstanding global loads
__device__ __forceinline__ void lgkm_barrier() {
    asm volatile("s_waitcnt lgkmcnt(0)" ::: "memory");
    __builtin_amdgcn_s_barrier();
    __builtin_amdgcn_sched_barrier(0);
}

// ---------------- kernel 0a: w_out (1024,128) f32 -> wbTf 16x16x32-B-frag tiled bf16 ------
// frag(z16, k32) lane l: z = z16*16 + (l&15), k = k32*32 + (l>>4)*8 + j   (z16 0..7, k32 0..31)
__global__ void k_transpose_wout(const float* __restrict__ w_out, short* __restrict__ wbTf) {
    __shared__ float t[64][65];
    int k0 = blockIdx.x * 64;   // 16 blocks over k=1024
    int z0 = blockIdx.y * 64;   // 2 blocks over z=128
    int tid = threadIdx.x;
    int c = tid & 63, rg = tid >> 6;
#pragma unroll
    for (int rr = 0; rr < 16; ++rr) {
        int kk = rg * 16 + rr;
        t[kk][c] = w_out[(size_t)(k0 + kk) * CZ + z0 + c];
    }
    __syncthreads();
#pragma unroll
    for (int l = 0; l < 2; ++l) {
        int id = l * 256 + tid;
        int f = id >> 6;               // 0..7: z16l = f>>1, k32l = f&1
        int z16l = f >> 1, k32l = f & 1;
        int ln = id & 63;
        int zl = z16l * 16 + (ln & 15);
        int kl = k32l * 32 + (ln >> 4) * 8;
        bf16x8 pk;
#pragma unroll
        for (int j = 0; j < 8; ++j) pk[j] = tobf16(t[kl + j][zl]);
        int z16 = blockIdx.y * 4 + z16l;
        int k32 = blockIdx.x * 2 + k32l;
        *(bf16x8*)(wbTf + ((size_t)(z16 * 32 + k32) * 64 + ln) * 8) = pk;
    }
}

// ---------------- kernel 0b: pack w1|w2 (256,32) -> wcT (64,256) bf16 ----------------
__global__ void k_pack_w12(const float* __restrict__ w1, const float* __restrict__ w2,
                           short* __restrict__ wcT) {
    int idx = blockIdx.x * 256 + threadIdx.x;
    int k = idx >> 6, n = idx & 63;
    float v = (n < 32) ? w1[k * CC + n] : w2[k * CC + (n - 32)];
    wcT[n * CM + k] = tobf16(v);
}

// ---------------- kernel 1: LayerNorm + projections -> aTf, bTf fragment-tiled bf16 ----------------
// aTf frag(fm16, ks32)[lane][8]: m = fm16*16 + (lane&15), s = ks32*32 + (lane>>4)*8 + j
__global__ __launch_bounds__(256) void k_ln_proj(
    const float* __restrict__ M, const float* __restrict__ ln_g, const float* __restrict__ ln_b,
    const float* __restrict__ b1, const float* __restrict__ b2,
    const short* __restrict__ wcT, short* __restrict__ aTf, short* __restrict__ bTf) {
    __shared__ short mnb[64 * 256];      // [s_loc][k] bf16, XOR-swizzled, 32 KB
    __shared__ short ab_s[2][32 * 72];   // [x][s_loc] stride-72 transpose buffers
    int r = blockIdx.x >> 1;
    int s0 = (blockIdx.x & 1) * 64;
    int tid = threadIdx.x, lane = tid & 63, w = tid >> 6;
    int g = lane >> 4, r16 = lane & 15;
    float4 gv = *(const float4*)(ln_g + lane * 4);
    float4 bv = *(const float4*)(ln_b + lane * 4);
    for (int it = 0; it < 16; ++it) {
        int sl = it * 4 + w;
        float4 v = *(const float4*)(M + ((size_t)(s0 + sl) * R_RES + r) * CM + lane * 4);
        float sum = v.x + v.y + v.z + v.w;
        float sq = v.x * v.x + v.y * v.y + v.z * v.z + v.w * v.w;
#pragma unroll
        for (int off = 32; off; off >>= 1) {
            sum += __shfl_xor(sum, off);
            sq  += __shfl_xor(sq, off);
        }
        float mu = sum * (1.0f / 256.0f);
        float var = sq * (1.0f / 256.0f) - mu * mu;
        float rstd = rsqrtf(var + 1e-5f);
        short4 mnp;
        mnp.x = tobf16((v.x - mu) * rstd * gv.x + bv.x);
        mnp.y = tobf16((v.y - mu) * rstd * gv.y + bv.y);
        mnp.z = tobf16((v.z - mu) * rstd * gv.z + bv.z);
        mnp.w = tobf16((v.w - mu) * rstd * gv.w + bv.w);
        int byte = sl * 512 + lane * 8;
        byte ^= ((sl & 7) << 4);
        *(short4*)((char*)mnb + byte) = mnp;
    }
    __syncthreads();
    f32x4 acc[4] = {{0,0,0,0},{0,0,0,0},{0,0,0,0},{0,0,0,0}};
    int srow = w * 16 + r16;
#pragma unroll
    for (int ks = 0; ks < 8; ++ks) {
        int byte = srow * 512 + ks * 64 + g * 16;
        byte ^= ((srow & 7) << 4);
        bf16x8 af = *(const bf16x8*)((const char*)mnb + byte);
#pragma unroll
        for (int nt = 0; nt < 4; ++nt) {
            bf16x8 bf = *(const bf16x8*)(wcT + (nt * 16 + r16) * CM + ks * 32 + g * 8);
            acc[nt] = __builtin_amdgcn_mfma_f32_16x16x32_bf16(af, bf, acc[nt], 0, 0, 0);
        }
    }
#pragma unroll
    for (int nt = 0; nt < 4; ++nt) {
        int n = nt * 16 + r16;
        int x = n & 31, sel = n >> 5;
        float bias = sel ? b2[x] : b1[x];
#pragma unroll
        for (int rr = 0; rr < 4; ++rr) {
            int sl = w * 16 + g * 4 + rr;
            ab_s[sel][x * 72 + sl] = tobf16(acc[nt][rr] + bias);
        }
    }
    __syncthreads();
    // fragment-tiled write-out: fm16 = r*2 + fl, ks32 = (s0>>5) + kl
    int piece = tid >> 6;            // 0..3
    int fl = piece >> 1, kl = piece & 1;
    int ln = tid & 63;
    int x = fl * 16 + (ln & 15);
    int s_loc = kl * 32 + (ln >> 4) * 8;
    i32x4 va = *(const i32x4*)((const char*)ab_s[0] + (x * 72 + s_loc) * 2);
    i32x4 vb = *(const i32x4*)((const char*)ab_s[1] + (x * 72 + s_loc) * 2);
    size_t off = ((((size_t)r * 2 + fl) * 4 + (s0 >> 5) + kl) * 64 + ln) * 16;
    *(i32x4*)((char*)aTf + off) = va;
    *(i32x4*)((char*)bTf + off) = vb;
}

// ---------------- kernel 2: persistent fused outer-product + w_out contraction ----------------
// 512 blocks x 512 thr (8 waves), 18 tiles/block of 128x128 O (4res x 4res).
// LDS 80 KB disjoint: B [0,32K), A2 [32K,64K), Pp [64K,80K) -> 2 blocks/CU.
// Per wave (kh,zq): wbT slice register-resident wb[2][16] (128 VGPR), loaded ONCE.
// ph2: 8m x 1n, A-frags rolling from L2, B from LDS. ph4: 16x16x32, zero global traffic.
__global__ __launch_bounds__(512, 4) void k_opm(
    const short* __restrict__ aTf, const short* __restrict__ bTf,
    const short* __restrict__ wbTf, const float* __restrict__ b_out,
    float* __restrict__ out) {
    __shared__ __align__(16) char smem[81920];
    int tid = threadIdx.x, lane = tid & 63, w = tid >> 6;
    int g = lane >> 4, r16 = lane & 15;
    int wm = w;                      // ph2: wave owns m-rows [wm*16, wm*16+16)
    int kh = w & 1, zq = w >> 1;     // ph4 role: k-half, z-quarter

    // ---- persistent wbT slice: z in [zq*32, +32), k in [kh*512, +512). 32 frags, static idx.
    bf16x8 wb[2][16];
#pragma unroll
    for (int zt = 0; zt < 2; ++zt)
#pragma unroll
        for (int ks2 = 0; ks2 < 16; ++ks2)
            wb[zt][ks2] = *(const bf16x8*)(wbTf +
                (((size_t)(zq * 2 + zt) * 32 + kh * 16 + ks2) * 64 + lane) * 8);

    int pR = tid >> 5;               // reduce role: p row (0..15)
    int zR = (tid & 31) * 4;         // reduce role: z quad
    float4 bo4 = *(const float4*)(b_out + zR);

    int t0 = blockIdx.x * 18;
    const char* Ab = (const char*)aTf;
    const char* Bb = (const char*)bTf;

    // ---- prologue: stage B(t0), prefetch af(t0, ks=0)
    {
        const char* gB = Bb + (size_t)(t0 % 96) * 32768;
#pragma unroll
        for (int q = 0; q < 4; ++q)
            __builtin_amdgcn_global_load_lds(
                (const __attribute__((address_space(1))) void*)(gB + q * 8192 + tid * 16),
                (__attribute__((address_space(3))) void*)(smem + q * 8192 + tid * 16), 16, 0, 0);
    }
    bf16x8 afc = *(const bf16x8*)(Ab + ((size_t)((t0 / 96) * 8 + wm) * 4 + 0) * 1024 + lane * 16);
    asm volatile("s_waitcnt vmcnt(0)" ::: "memory");
    __syncthreads();

    for (int it = 0; it < 18; ++it) {
        int t = t0 + it;
        int bi = t / 96, bj = t % 96;
        int tn = (it < 17) ? t + 1 : t0;
        const char* gAc = Ab + (size_t)(bi * 8 + wm) * 4096;
        const char* gAn = Ab + (size_t)((tn / 96) * 8 + wm) * 4096;

        // ---- ph2: O[128x128]; acc[ni]: m = wm*16 + r16, n = ni*16 + g*4 + rr
        f32x4 acc[8] = {};
#pragma unroll
        for (int ks = 0; ks < 4; ++ks) {
            bf16x8 bf[8];
#pragma unroll
            for (int ni = 0; ni < 8; ++ni)
                bf[ni] = *(const bf16x8*)(smem + ((ni * 4 + ks) * 64 + lane) * 16);
            bf16x8 afn = (ks < 3)
                ? *(const bf16x8*)(gAc + (ks + 1) * 1024 + lane * 16)
                : *(const bf16x8*)(gAn + lane * 16);
            __builtin_amdgcn_s_setprio(1);
#pragma unroll
            for (int ni = 0; ni < 8; ++ni)
                acc[ni] = __builtin_amdgcn_mfma_f32_16x16x32_bf16(bf[ni], afc, acc[ni], 0, 0, 0);
            __builtin_amdgcn_s_setprio(0);
            afc = afn;
        }
        lgkm_barrier();   // B LDS reads done

        // ---- stage B(t+1) into [0,32K) (overlaps ph3/ph4; drains at loop-top vmcnt)
        if (it < 17) {
            const char* gB = Bb + (size_t)(tn % 96) * 32768;
#pragma unroll
            for (int q = 0; q < 4; ++q)
                __builtin_amdgcn_global_load_lds(
                    (const __attribute__((address_space(1))) void*)(gB + q * 8192 + tid * 16),
                    (__attribute__((address_space(3))) void*)(smem + q * 8192 + tid * 16), 16, 0, 0);
        }

        // ---- ph3: O -> A2 bf16 [p = i*4+j][k = x*32+y] in [32K,64K), dual-XOR swizzle
#pragma unroll
        for (int ni = 0; ni < 8; ++ni) {
            int x = (wm & 1) * 16 + r16;
            int p = (wm >> 1) * 4 + (ni >> 1);
            int y0 = (ni & 1) * 16 + g * 4;
            int byte = (p * 2048 + x * 64 + y0 * 2) ^ (((p & 7) ^ (x & 7)) << 4);
            short4 pk;
            pk.x = tobf16(acc[ni][0]);
            pk.y = tobf16(acc[ni][1]);
            pk.z = tobf16(acc[ni][2]);
            pk.w = tobf16(acc[ni][3]);
            *(short4*)(smem + 32768 + byte) = pk;
        }
        lgkm_barrier();   // A2 visible

        // ---- ph4: out[16p][128z]; wave (kh,zq); wb from REGISTERS, A2 from LDS
        f32x4 c0 = {0,0,0,0}, c1 = {0,0,0,0};
#pragma unroll
        for (int ks2 = 0; ks2 < 16; ++ks2) {
            int x = kh * 16 + ks2;
            int abyte = (r16 * 2048 + x * 64 + g * 16) ^ ((((r16 & 7) ^ (x & 7))) << 4);
            bf16x8 a2f = *(const bf16x8*)(smem + 32768 + abyte);
            c0 = __builtin_amdgcn_mfma_f32_16x16x32_bf16(wb[0][ks2], a2f, c0, 0, 0, 0);
            c1 = __builtin_amdgcn_mfma_f32_16x16x32_bf16(wb[1][ks2], a2f, c1, 0, 0, 0);
        }
        // Pp[kh][p=r16][z] f32 in [64K,80K), ^((r16&7)<<4)
        {
            int b0 = (kh * 8192 + r16 * 512 + (zq * 32 + g * 4) * 4) ^ ((r16 & 7) << 4);
            int b1 = (kh * 8192 + r16 * 512 + (zq * 32 + 16 + g * 4) * 4) ^ ((r16 & 7) << 4);
            *(f32x4*)(smem + 65536 + b0) = c0;
            *(f32x4*)(smem + 65536 + b1) = c1;
        }
        lgkm_barrier();   // Pp visible

        // ---- reduce kh-halves + coalesced f32x4 store
        {
            int base = (pR * 512 + zR * 4) ^ ((pR & 7) << 4);
            f32x4 v0 = *(const f32x4*)(smem + 65536 + base);
            f32x4 v1 = *(const f32x4*)(smem + 65536 + 8192 + base);
            f32x4 res;
            res[0] = (v0[0] + v1[0] + bo4.x) * (1.0f / 128.0f);
            res[1] = (v0[1] + v1[1] + bo4.y) * (1.0f / 128.0f);
            res[2] = (v0[2] + v1[2] + bo4.z) * (1.0f / 128.0f);
            res[3] = (v0[3] + v1[3] + bo4.w) * (1.0f / 128.0f);
            int ig = bi * 4 + (pR >> 2);
            int jg = bj * 4 + (pR & 3);
            *(f32x4*)(out + ((size_t)ig * R_RES + jg) * CZ + zR) = res;
        }

        // ---- loop-top barrier: drain B(t+1) staging + af prefetch, protect Pp reads
        asm volatile("s_waitcnt vmcnt(0)" ::: "memory");
        __syncthreads();
    }
}

extern "C" void kernel_launch(void* const* d_in, const int* in_sizes, int n_in,
                              void* d_out, int out_size, void* d_ws, size_t ws_size,
                              hipStream_t stream) {
    const float* M     = (const float*)d_in[0];
    const float* ln_g  = (const float*)d_in[1];
    const float* ln_b  = (const float*)d_in[2];
    const float* w1    = (const float*)d_in[3];
    const float* b1    = (const float*)d_in[4];
    const float* w2    = (const float*)d_in[5];
    const float* b2    = (const float*)d_in[6];
    const float* w_out = (const float*)d_in[7];
    const float* b_out = (const float*)d_in[8];
    float* out = (float*)d_out;

    short* aTf  = (short*)d_ws;             // 12288 x 128 bf16, fragment-tiled
    short* bTf  = aTf + 12288 * 128;        // 12288 x 128 bf16, fragment-tiled
    short* wbTf = bTf + 12288 * 128;        // 128 x 1024 bf16, 16x16-B-frag tiled
    short* wcT  = wbTf + 128 * 1024;        // 64 x 256 bf16

    k_transpose_wout<<<dim3(16, 2), 256, 0, stream>>>(w_out, wbTf);
    k_pack_w12<<<64, 256, 0, stream>>>(w1, w2, wcT);
    k_ln_proj<<<768, 256, 0, stream>>>(M, ln_g, ln_b, b1, b2, wcT, aTf, bTf);
    k_opm<<<512, 512, 0, stream>>>(aTf, bTf, wbTf, b_out, out);
}

// Round 10
// 125.999 us; speedup vs baseline: 3.2527x; 3.2527x over previous
//
#include <hip/hip_runtime.h>
#include <hip/hip_bf16.h>

#define R_RES 384
#define S_SEQ 128
#define CM 256
#define CC 32
#define CZ 128

typedef __attribute__((ext_vector_type(8))) short bf16x8;
typedef __attribute__((ext_vector_type(4))) float f32x4;
typedef __attribute__((ext_vector_type(4))) int i32x4;

__device__ __forceinline__ short tobf16(float f) {
    union { __hip_bfloat16 h; short s; } u;
    u.h = __float2bfloat16(f);
    return u.s;
}

// lgkm-only barrier: LDS visibility without draining outstanding global loads
__device__ __forceinline__ void lgkm_barrier() {
    asm volatile("s_waitcnt lgkmcnt(0)" ::: "memory");
    __builtin_amdgcn_s_barrier();
    __builtin_amdgcn_sched_barrier(0);
}

// ---------------- kernel 0a: w_out (1024,128) f32 -> wbTf 16x16x32-B-frag tiled bf16 ------
// frag(z16, k32) lane l: z = z16*16 + (l&15), k = k32*32 + (l>>4)*8 + j   (z16 0..7, k32 0..31)
__global__ void k_transpose_wout(const float* __restrict__ w_out, short* __restrict__ wbTf) {
    __shared__ float t[64][65];
    int k0 = blockIdx.x * 64;   // 16 blocks over k=1024
    int z0 = blockIdx.y * 64;   // 2 blocks over z=128
    int tid = threadIdx.x;
    int c = tid & 63, rg = tid >> 6;
#pragma unroll
    for (int rr = 0; rr < 16; ++rr) {
        int kk = rg * 16 + rr;
        t[kk][c] = w_out[(size_t)(k0 + kk) * CZ + z0 + c];
    }
    __syncthreads();
#pragma unroll
    for (int l = 0; l < 2; ++l) {
        int id = l * 256 + tid;
        int f = id >> 6;               // 0..7: z16l = f>>1, k32l = f&1
        int z16l = f >> 1, k32l = f & 1;
        int ln = id & 63;
        int zl = z16l * 16 + (ln & 15);
        int kl = k32l * 32 + (ln >> 4) * 8;
        bf16x8 pk;
#pragma unroll
        for (int j = 0; j < 8; ++j) pk[j] = tobf16(t[kl + j][zl]);
        int z16 = blockIdx.y * 4 + z16l;
        int k32 = blockIdx.x * 2 + k32l;
        *(bf16x8*)(wbTf + ((size_t)(z16 * 32 + k32) * 64 + ln) * 8) = pk;
    }
}

// ---------------- kernel 0b: pack w1|w2 (256,32) -> wcT (64,256) bf16 ----------------
__global__ void k_pack_w12(const float* __restrict__ w1, const float* __restrict__ w2,
                           short* __restrict__ wcT) {
    int idx = blockIdx.x * 256 + threadIdx.x;
    int k = idx >> 6, n = idx & 63;
    float v = (n < 32) ? w1[k * CC + n] : w2[k * CC + (n - 32)];
    wcT[n * CM + k] = tobf16(v);
}

// ---------------- kernel 1: LayerNorm + projections -> aTf, bTf fragment-tiled bf16 ----------------
// aTf frag(fm16, ks32)[lane][8]: m = fm16*16 + (lane&15), s = ks32*32 + (lane>>4)*8 + j
__global__ __launch_bounds__(256) void k_ln_proj(
    const float* __restrict__ M, const float* __restrict__ ln_g, const float* __restrict__ ln_b,
    const float* __restrict__ b1, const float* __restrict__ b2,
    const short* __restrict__ wcT, short* __restrict__ aTf, short* __restrict__ bTf) {
    __shared__ short mnb[64 * 256];      // [s_loc][k] bf16, XOR-swizzled, 32 KB
    __shared__ short ab_s[2][32 * 72];   // [x][s_loc] stride-72 transpose buffers
    int r = blockIdx.x >> 1;
    int s0 = (blockIdx.x & 1) * 64;
    int tid = threadIdx.x, lane = tid & 63, w = tid >> 6;
    int g = lane >> 4, r16 = lane & 15;
    float4 gv = *(const float4*)(ln_g + lane * 4);
    float4 bv = *(const float4*)(ln_b + lane * 4);
    for (int it = 0; it < 16; ++it) {
        int sl = it * 4 + w;
        float4 v = *(const float4*)(M + ((size_t)(s0 + sl) * R_RES + r) * CM + lane * 4);
        float sum = v.x + v.y + v.z + v.w;
        float sq = v.x * v.x + v.y * v.y + v.z * v.z + v.w * v.w;
#pragma unroll
        for (int off = 32; off; off >>= 1) {
            sum += __shfl_xor(sum, off);
            sq  += __shfl_xor(sq, off);
        }
        float mu = sum * (1.0f / 256.0f);
        float var = sq * (1.0f / 256.0f) - mu * mu;
        float rstd = rsqrtf(var + 1e-5f);
        short4 mnp;
        mnp.x = tobf16((v.x - mu) * rstd * gv.x + bv.x);
        mnp.y = tobf16((v.y - mu) * rstd * gv.y + bv.y);
        mnp.z = tobf16((v.z - mu) * rstd * gv.z + bv.z);
        mnp.w = tobf16((v.w - mu) * rstd * gv.w + bv.w);
        int byte = sl * 512 + lane * 8;
        byte ^= ((sl & 7) << 4);
        *(short4*)((char*)mnb + byte) = mnp;
    }
    __syncthreads();
    f32x4 acc[4] = {{0,0,0,0},{0,0,0,0},{0,0,0,0},{0,0,0,0}};
    int srow = w * 16 + r16;
#pragma unroll
    for (int ks = 0; ks < 8; ++ks) {
        int byte = srow * 512 + ks * 64 + g * 16;
        byte ^= ((srow & 7) << 4);
        bf16x8 af = *(const bf16x8*)((const char*)mnb + byte);
#pragma unroll
        for (int nt = 0; nt < 4; ++nt) {
            bf16x8 bf = *(const bf16x8*)(wcT + (nt * 16 + r16) * CM + ks * 32 + g * 8);
            acc[nt] = __builtin_amdgcn_mfma_f32_16x16x32_bf16(af, bf, acc[nt], 0, 0, 0);
        }
    }
#pragma unroll
    for (int nt = 0; nt < 4; ++nt) {
        int n = nt * 16 + r16;
        int x = n & 31, sel = n >> 5;
        float bias = sel ? b2[x] : b1[x];
#pragma unroll
        for (int rr = 0; rr < 4; ++rr) {
            int sl = w * 16 + g * 4 + rr;
            ab_s[sel][x * 72 + sl] = tobf16(acc[nt][rr] + bias);
        }
    }
    __syncthreads();
    // fragment-tiled write-out: fm16 = r*2 + fl, ks32 = (s0>>5) + kl
    int piece = tid >> 6;            // 0..3
    int fl = piece >> 1, kl = piece & 1;
    int ln = tid & 63;
    int x = fl * 16 + (ln & 15);
    int s_loc = kl * 32 + (ln >> 4) * 8;
    i32x4 va = *(const i32x4*)((const char*)ab_s[0] + (x * 72 + s_loc) * 2);
    i32x4 vb = *(const i32x4*)((const char*)ab_s[1] + (x * 72 + s_loc) * 2);
    size_t off = ((((size_t)r * 2 + fl) * 4 + (s0 >> 5) + kl) * 64 + ln) * 16;
    *(i32x4*)((char*)aTf + off) = va;
    *(i32x4*)((char*)bTf + off) = vb;
}

// ---------------- kernel 2: persistent fused outer-product + w_out contraction ----------------
// 512 blocks x 512 thr (8 waves), 18 tiles/block of 128x128 O (4res x 4res).
// __launch_bounds__(512,2): 256-VGPR cap so wb[2][16] (128 VGPR) is GENUINELY register-resident.
// 1 block/CU. LDS 112 KB: B dbuf 2x32K [0,64K), A2 [64K,96K), Pp [96K,112K).
// B(t+1) staged at ph2(t) start (into the other buffer) -> loop-top drain is free.
__global__ __launch_bounds__(512, 2) void k_opm(
    const short* __restrict__ aTf, const short* __restrict__ bTf,
    const short* __restrict__ wbTf, const float* __restrict__ b_out,
    float* __restrict__ out) {
    __shared__ __align__(16) char smem[114688];
    int tid = threadIdx.x, lane = tid & 63, w = tid >> 6;
    int g = lane >> 4, r16 = lane & 15;
    int wm = w;                      // ph2: wave owns m-rows [wm*16, wm*16+16)
    int kh = w & 1, zq = w >> 1;     // ph4 role: k-half, z-quarter

    // ---- persistent wbT slice: z in [zq*32, +32), k in [kh*512, +512). 32 frags, static idx.
    bf16x8 wb[2][16];
#pragma unroll
    for (int zt = 0; zt < 2; ++zt)
#pragma unroll
        for (int ks2 = 0; ks2 < 16; ++ks2)
            wb[zt][ks2] = *(const bf16x8*)(wbTf +
                (((size_t)(zq * 2 + zt) * 32 + kh * 16 + ks2) * 64 + lane) * 8);

    int pR = tid >> 5;               // reduce role: p row (0..15)
    int zR = (tid & 31) * 4;         // reduce role: z quad
    float4 bo4 = *(const float4*)(b_out + zR);

    int t0 = blockIdx.x * 18;
    const char* Ab = (const char*)aTf;
    const char* Bb = (const char*)bTf;

    // ---- prologue: stage B(t0) -> buf0, prefetch af(t0, ks=0)
    {
        const char* gB = Bb + (size_t)(t0 % 96) * 32768;
#pragma unroll
        for (int q = 0; q < 4; ++q)
            __builtin_amdgcn_global_load_lds(
                (const __attribute__((address_space(1))) void*)(gB + q * 8192 + tid * 16),
                (__attribute__((address_space(3))) void*)(smem + q * 8192 + tid * 16), 16, 0, 0);
    }
    bf16x8 afc = *(const bf16x8*)(Ab + (size_t)((t0 / 96) * 8 + wm) * 4096 + lane * 16);
    asm volatile("s_waitcnt vmcnt(0)" ::: "memory");
    __syncthreads();

    for (int it = 0; it < 18; ++it) {
        int t = t0 + it;
        int bi = t / 96, bj = t % 96;
        int tn = (it < 17) ? t + 1 : t0;
        const char* gAc = Ab + (size_t)(bi * 8 + wm) * 4096;
        const char* gAn = Ab + (size_t)((tn / 96) * 8 + wm) * 4096;
        char* Bcur = smem + (it & 1) * 32768;

        // ---- stage B(t+1) into the OTHER buffer (overlaps ph2..ph4; drains at loop-top)
        if (it < 17) {
            const char* gB = Bb + (size_t)(tn % 96) * 32768;
            char* Bnxt = smem + ((it + 1) & 1) * 32768;
#pragma unroll
            for (int q = 0; q < 4; ++q)
                __builtin_amdgcn_global_load_lds(
                    (const __attribute__((address_space(1))) void*)(gB + q * 8192 + tid * 16),
                    (__attribute__((address_space(3))) void*)(Bnxt + q * 8192 + tid * 16), 16, 0, 0);
        }

        // ---- ph2: O[128x128]; acc[ni]: m = wm*16 + r16, n = ni*16 + g*4 + rr
        f32x4 acc[8] = {};
#pragma unroll
        for (int ks = 0; ks < 4; ++ks) {
            bf16x8 bf[8];
#pragma unroll
            for (int ni = 0; ni < 8; ++ni)
                bf[ni] = *(const bf16x8*)(Bcur + ((ni * 4 + ks) * 64 + lane) * 16);
            bf16x8 afn = (ks < 3)
                ? *(const bf16x8*)(gAc + (ks + 1) * 1024 + lane * 16)
                : *(const bf16x8*)(gAn + lane * 16);
            __builtin_amdgcn_s_setprio(1);
#pragma unroll
            for (int ni = 0; ni < 8; ++ni)
                acc[ni] = __builtin_amdgcn_mfma_f32_16x16x32_bf16(bf[ni], afc, acc[ni], 0, 0, 0);
            __builtin_amdgcn_s_setprio(0);
            afc = afn;
        }
        lgkm_barrier();   // B(cur) LDS reads done (also orders prev-tile A2/Pp reads)

        // ---- ph3: O -> A2 bf16 [p = i*4+j][k = x*32+y] in [64K,96K), dual-XOR swizzle
#pragma unroll
        for (int ni = 0; ni < 8; ++ni) {
            int x = (wm & 1) * 16 + r16;
            int p = (wm >> 1) * 4 + (ni >> 1);
            int y0 = (ni & 1) * 16 + g * 4;
            int byte = (p * 2048 + x * 64 + y0 * 2) ^ (((p & 7) ^ (x & 7)) << 4);
            short4 pk;
            pk.x = tobf16(acc[ni][0]);
            pk.y = tobf16(acc[ni][1]);
            pk.z = tobf16(acc[ni][2]);
            pk.w = tobf16(acc[ni][3]);
            *(short4*)(smem + 65536 + byte) = pk;
        }
        lgkm_barrier();   // A2 visible

        // ---- ph4: out[16p][128z]; wave (kh,zq); wb from REGISTERS, A2 from LDS
        f32x4 c0 = {0,0,0,0}, c1 = {0,0,0,0};
#pragma unroll
        for (int ks2 = 0; ks2 < 16; ++ks2) {
            int x = kh * 16 + ks2;
            int abyte = (r16 * 2048 + x * 64 + g * 16) ^ ((((r16 & 7) ^ (x & 7))) << 4);
            bf16x8 a2f = *(const bf16x8*)(smem + 65536 + abyte);
            c0 = __builtin_amdgcn_mfma_f32_16x16x32_bf16(wb[0][ks2], a2f, c0, 0, 0, 0);
            c1 = __builtin_amdgcn_mfma_f32_16x16x32_bf16(wb[1][ks2], a2f, c1, 0, 0, 0);
        }
        // Pp[kh][p=r16][z] f32 in [96K,112K), ^((r16&7)<<4)
        {
            int b0 = (kh * 8192 + r16 * 512 + (zq * 32 + g * 4) * 4) ^ ((r16 & 7) << 4);
            int b1 = (kh * 8192 + r16 * 512 + (zq * 32 + 16 + g * 4) * 4) ^ ((r16 & 7) << 4);
            *(f32x4*)(smem + 98304 + b0) = c0;
            *(f32x4*)(smem + 98304 + b1) = c1;
        }
        lgkm_barrier();   // Pp visible

        // ---- reduce kh-halves + coalesced f32x4 store
        {
            int base = (pR * 512 + zR * 4) ^ ((pR & 7) << 4);
            f32x4 v0 = *(const f32x4*)(smem + 98304 + base);
            f32x4 v1 = *(const f32x4*)(smem + 98304 + 8192 + base);
            f32x4 res;
            res[0] = (v0[0] + v1[0] + bo4.x) * (1.0f / 128.0f);
            res[1] = (v0[1] + v1[1] + bo4.y) * (1.0f / 128.0f);
            res[2] = (v0[2] + v1[2] + bo4.z) * (1.0f / 128.0f);
            res[3] = (v0[3] + v1[3] + bo4.w) * (1.0f / 128.0f);
            int ig = bi * 4 + (pR >> 2);
            int jg = bj * 4 + (pR & 3);
            *(f32x4*)(out + ((size_t)ig * R_RES + jg) * CZ + zR) = res;
        }

        // ---- loop-top barrier: B(t+1) staged long ago (drain ~free); protects A2/Pp WAR
        asm volatile("s_waitcnt vmcnt(0)" ::: "memory");
        __syncthreads();
    }
}

extern "C" void kernel_launch(void* const* d_in, const int* in_sizes, int n_in,
                              void* d_out, int out_size, void* d_ws, size_t ws_size,
                              hipStream_t stream) {
    const float* M     = (const float*)d_in[0];
    const float* ln_g  = (const float*)d_in[1];
    const float* ln_b  = (const float*)d_in[2];
    const float* w1    = (const float*)d_in[3];
    const float* b1    = (const float*)d_in[4];
    const float* w2    = (const float*)d_in[5];
    const float* b2    = (const float*)d_in[6];
    const float* w_out = (const float*)d_in[7];
    const float* b_out = (const float*)d_in[8];
    float* out = (float*)d_out;

    short* aTf  = (short*)d_ws;             // 12288 x 128 bf16, fragment-tiled
    short* bTf  = aTf + 12288 * 128;        // 12288 x 128 bf16, fragment-tiled
    short* wbTf = bTf + 12288 * 128;        // 128 x 1024 bf16, 16x16-B-frag tiled
    short* wcT  = wbTf + 128 * 1024;        // 64 x 256 bf16

    k_transpose_wout<<<dim3(16, 2), 256, 0, stream>>>(w_out, wbTf);
    k_pack_w12<<<64, 256, 0, stream>>>(w1, w2, wcT);
    k_ln_proj<<<768, 256, 0, stream>>>(M, ln_g, ln_b, b1, b2, wcT, aTf, bTf);
    k_opm<<<512, 512, 0, stream>>>(aTf, bTf, wbTf, b_out, out);
}